// Round 5
// baseline (176.174 us; speedup 1.0000x reference)
//
#include <hip/hip_runtime.h>
#include <stdint.h>

#define M_DIM 2048
#define N_DIM 4096
#define K_DIM 4096
#define NGROUP 32
#define GSIZE 128

#define RQ_UP   (127.0f / 15.0f)   // weight requant gain
#define RQ_DOWN (15.0f / 127.0f)

// ---------------------------------------------------------------------------
// R5: same geometry as R4 (128x128 tile, 4 waves 2Mx2N, wave 64x64 = 4x4
// frags of 16x16x64 i8 MFMA, 4 LDS slots, distance-3 prefetch, 2 blocks/CU).
// CHANGED: sync plumbing only.
//  - barriers = __builtin_amdgcn_s_barrier()  (no fence -> no vmcnt(0) drain)
//  - waits    = bare asm volatile s_waitcnt, NO "memory" clobber, pinned by
//               sched_barrier(0)  (memory-clobber asm provokes the waitcnt
//               pass into inserting vmcnt(0) before it -> R1-R4 were secretly
//               drained 2-phase, explaining the flat 25-26% MfmaUtil)
//  - fragment reads = one opaque asm block: 8x ds_read_b128 + lgkmcnt(0),
//               early-clobber outputs; MFMAs consume its SSA outputs so the
//               rule-#18 hoist hazard cannot occur, and no visible C++ LDS
//               read remains in the hot loop for the compiler to protect.
// LDS swizzle (verified 0 conflicts R1-R4): 16B chunk c of 64B row r at slot
// c ^ ((r>>1)&3); DMA-side csrc = (lane&3) ^ ((lane>>3)&3).
// ---------------------------------------------------------------------------
#define BM 128
#define BN 128
#define KSLICE 64
#define NSLICE (K_DIM / KSLICE)    // 64
#define ASLOT (BM * KSLICE)        //  8 KiB
#define BSLOT (BN * KSLICE)        //  8 KiB

typedef __attribute__((ext_vector_type(4))) int int32x4_t;

static __device__ __forceinline__ void gl2lds16(const void* g, void* l) {
    auto gp = (const __attribute__((address_space(1))) unsigned int*)(uintptr_t)g;
    auto lp = (__attribute__((address_space(3))) unsigned int*)(uintptr_t)l;
    __builtin_amdgcn_global_load_lds(gp, lp, 16, 0, 0);
}

// bare counted wait: no clobber (see header comment), pinned by sched_barrier
#define WAITVM_(N) asm volatile("s_waitcnt vmcnt(" #N ")")
#define WAITVM(N)                                   \
    do {                                            \
        __builtin_amdgcn_sched_barrier(0);          \
        WAITVM_(N);                                 \
        __builtin_amdgcn_sched_barrier(0);          \
    } while (0)

// ---------------------------------------------------------------------------
// Fused prep:
//   [0, 2048): per-token activation quant -> A8 = (q-128) int8, xscale, czp
//   [2048, ..): weight requant; rsn computed in-cluster via shfl_xor max.
// R5: activation quant uses inv_sc multiply (1 divide/thread instead of 16).
// ---------------------------------------------------------------------------
#define QUANT_BLOCKS M_DIM
#define DEQ_BLOCKS ((N_DIM * K_DIM) / 8 / 256)       // 8 codes / thread

__global__ __launch_bounds__(256) void prep_kernel(
        const float* __restrict__ x,
        const int* __restrict__ qw,          // [N][K] codes 0..15 as int32
        const float* __restrict__ wsc,       // [N][32]
        const int* __restrict__ wzp,         // [N][32]
        char* __restrict__ A8,               // [M][K] int8 (q-128)
        char* __restrict__ Bt8,              // [N][K] int8 requantized
        float* __restrict__ xscale,          // [M]
        float* __restrict__ xzpc,            // [M]  = 128 - zp
        int* __restrict__ Sw)                // [N][32] group sums of Bt8
{
    const int t = threadIdx.x;
    if (blockIdx.x < QUANT_BLOCKS) {
        const int s = blockIdx.x;
        const float* xrow = x + (size_t)s * K_DIM;

        float xv[16];
        float vmin = 1e38f, vmax = -1e38f;
#pragma unroll
        for (int p = 0; p < 4; ++p) {
            float4 v = *((const float4*)(xrow + p * 1024) + t);
            xv[p*4+0] = v.x; xv[p*4+1] = v.y; xv[p*4+2] = v.z; xv[p*4+3] = v.w;
            vmin = fminf(vmin, fminf(fminf(v.x, v.y), fminf(v.z, v.w)));
            vmax = fmaxf(vmax, fmaxf(fmaxf(v.x, v.y), fmaxf(v.z, v.w)));
        }
#pragma unroll
        for (int off = 32; off > 0; off >>= 1) {
            vmin = fminf(vmin, __shfl_xor(vmin, off));
            vmax = fmaxf(vmax, __shfl_xor(vmax, off));
        }
        __shared__ float smin[4], smax[4];
        const int wave = t >> 6;
        if ((t & 63) == 0) { smin[wave] = vmin; smax[wave] = vmax; }
        __syncthreads();
        vmin = fminf(fminf(smin[0], smin[1]), fminf(smin[2], smin[3]));
        vmax = fmaxf(fmaxf(smax[0], smax[1]), fmaxf(smax[2], smax[3]));

        float sc = (vmax - vmin) / 255.0f;
        sc = fmaxf(sc, 1e-5f);
        float zp = rintf(-vmin / sc);
        zp = fminf(fmaxf(zp, 0.0f), 255.0f);
        const float inv_sc = 1.0f / sc;

#pragma unroll
        for (int p = 0; p < 4; ++p) {
            int b[4];
#pragma unroll
            for (int e = 0; e < 4; ++e) {
                float q = fminf(fmaxf(rintf(xv[p*4+e] * inv_sc) + zp, 0.0f), 255.0f);
                b[e] = (int)q - 128;
            }
            unsigned pack = (b[0] & 0xff) | ((b[1] & 0xff) << 8) |
                            ((b[2] & 0xff) << 16) | ((b[3] & 0xff) << 24);
            *(unsigned*)(A8 + (size_t)s * K_DIM + p * 1024 + t * 4) = pack;
        }
        if (t == 0) { xscale[s] = sc; xzpc[s] = 128.0f - zp; }
    } else {
        // ---- weight requant: 8 codes/thread; 16-lane cluster = 1 group ----
        const size_t base = ((size_t)(blockIdx.x - QUANT_BLOCKS) * 256 + t) * 8;
        const int n = (int)(base >> 12);          // /4096
        const int g = (int)((base >> 7) & 31);
        const int zp = wzp[n * NGROUP + g];

        // inline rsn: row max of the 32 scales across the 16-lane cluster
        const int cl = t & 15;
        float2 wp = *(const float2*)(wsc + (size_t)n * NGROUP + cl * 2);
        float smx = fmaxf(wp.x, wp.y);
#pragma unroll
        for (int off = 1; off < 16; off <<= 1)
            smx = fmaxf(smx, __shfl_xor(smx, off));
        const float factor = wsc[n * NGROUP + g] * (RQ_UP / smx);   // <= 127/15

        int4 c0 = *(const int4*)(qw + base);
        int4 c1 = *(const int4*)(qw + base + 4);
        int w[8];
        w[0] = (int)rintf((float)(c0.x - zp) * factor);
        w[1] = (int)rintf((float)(c0.y - zp) * factor);
        w[2] = (int)rintf((float)(c0.z - zp) * factor);
        w[3] = (int)rintf((float)(c0.w - zp) * factor);
        w[4] = (int)rintf((float)(c1.x - zp) * factor);
        w[5] = (int)rintf((float)(c1.y - zp) * factor);
        w[6] = (int)rintf((float)(c1.z - zp) * factor);
        w[7] = (int)rintf((float)(c1.w - zp) * factor);
        uint2 pk;
        pk.x = (w[0] & 0xff) | ((w[1] & 0xff) << 8) | ((w[2] & 0xff) << 16) | ((w[3] & 0xff) << 24);
        pk.y = (w[4] & 0xff) | ((w[5] & 0xff) << 8) | ((w[6] & 0xff) << 16) | ((w[7] & 0xff) << 24);
        *(uint2*)(Bt8 + base) = pk;

        int s8 = w[0] + w[1] + w[2] + w[3] + w[4] + w[5] + w[6] + w[7];
#pragma unroll
        for (int off = 1; off < 16; off <<= 1) s8 += __shfl_xor(s8, off);
        if ((t & 15) == 0)
            Sw[n * NGROUP + g] = s8;     // coalesced, no atomic
    }
}

// ---------------------------------------------------------------------------
// Pipelined i8 GEMM, 2 blocks/CU, counted vmcnt that actually reaches HW.
// Epilogue: out[m][n] = xscale[m]*(fws[n]*iacc + czp[m]*WSf[n]) + bias[n]
// ---------------------------------------------------------------------------
__global__ __launch_bounds__(256, 2) void gemm_kernel(
        const char* __restrict__ A8,     // [M][K] int8
        const char* __restrict__ Bt8,    // [N][K] int8
        const float* __restrict__ xscale,
        const float* __restrict__ xzpc,
        const float* __restrict__ wsc,   // [N][32]
        const int* __restrict__ Sw,      // [N][32]
        const float* __restrict__ bias,  // [N]
        float* __restrict__ out)         // [M][N] f32
{
    __shared__ __align__(16) char As[4][ASLOT];   // 32 KiB
    __shared__ __align__(16) char Bs[4][BSLOT];   // 32 KiB
    __shared__ float fws_s[BN], wsf_s[BN];

    const int tid  = threadIdx.x;
    const int bn   = blockIdx.x;
    const int bm   = blockIdx.y;
    const int wave = tid >> 6;           // 0..3
    const int lane = tid & 63;
    const int wr   = wave >> 1;          // 0..1 -> 64-row band
    const int wcl  = wave & 1;           // 0..1 -> 64-col band
    const int lrow  = lane & 15;
    const int lquad = lane >> 4;         // 0..3 -> 16B k-chunk

    // --- per-column epilogue constants, before the pipeline starts ---
    if (tid < BN) {
        const int n = bn * BN + tid;
        const int4* s4 = (const int4*)(Sw + (size_t)n * NGROUP);
        int acc = 0;
#pragma unroll
        for (int p = 0; p < 8; ++p) { int4 v = s4[p]; acc += v.x + v.y + v.z + v.w; }
        const float4* w4 = (const float4*)(wsc + (size_t)n * NGROUP);
        float s = 0.f;
#pragma unroll
        for (int p = 0; p < 8; ++p) {
            float4 w = w4[p];
            s = fmaxf(s, fmaxf(fmaxf(w.x, w.y), fmaxf(w.z, w.w)));
        }
        const float fw = s * RQ_DOWN;
        fws_s[tid] = fw;
        wsf_s[tid] = fw * (float)acc;
    }
    // drain to a clean vmcnt/lgkm baseline (once, outside the hot loop)
    __builtin_amdgcn_sched_barrier(0);
    asm volatile("s_waitcnt vmcnt(0) lgkmcnt(0)");
    __builtin_amdgcn_sched_barrier(0);

    // --- staging: gl2lds dst = uniform base + lane*16 (m104). Each DMA
    // covers 16 rows x 64B; wave w instr p covers rows (p*4+w)*16.. ---
    const char* Ab = A8  + (size_t)(bm * BM) * K_DIM;
    const char* Bb = Bt8 + (size_t)(bn * BN) * K_DIM;
    const int lsub = lane >> 2;                    // row within 16-row slab
    const int csrc = (lane & 3) ^ ((lane >> 3) & 3);
    const char* gA0 = Ab + (size_t)((wave * 16     ) + lsub) * K_DIM + csrc * 16;
    const char* gA1 = Ab + (size_t)((wave * 16 + 64) + lsub) * K_DIM + csrc * 16;
    const char* gB0 = Bb + (size_t)((wave * 16     ) + lsub) * K_DIM + csrc * 16;
    const char* gB1 = Bb + (size_t)((wave * 16 + 64) + lsub) * K_DIM + csrc * 16;
    const int lOF = wave * 1024;                   // + 4096 for the +64-row slab

    // --- ds_read base offsets (LDS 32-bit addresses for asm ds_read).
    // Truncating the flat address of a __shared__ object yields the LDS
    // offset (same cast the proven gl2lds16 path uses).
    const int xq = (lquad ^ ((lrow >> 1) & 3)) * 16;
    const unsigned asBase = (unsigned)(uintptr_t)&As[0][0];
    const unsigned bsBase = (unsigned)(uintptr_t)&Bs[0][0];
    // frag i address = base + slot*8192 + (band*64 + i*16 + lrow)*64 + xq;
    // i-stride is 1024 -> fold into ds_read offset immediates.
    const unsigned aOff0 = (unsigned)((wr  * 64 + lrow) * KSLICE + xq);
    const unsigned bOff0 = (unsigned)((wcl * 64 + lrow) * KSLICE + xq);

    int32x4_t iacc[4][4];
    const int32x4_t zi = {0, 0, 0, 0};
#pragma unroll
    for (int i = 0; i < 4; ++i)
#pragma unroll
        for (int j = 0; j < 4; ++j) iacc[i][j] = zi;

#define STAGE(t) {                                                    \
        const int sl_ = (t) & 3;                                      \
        const size_t k0_ = (size_t)(t) * KSLICE;                      \
        gl2lds16(gA0 + k0_, &As[sl_][0] + lOF);                       \
        gl2lds16(gA1 + k0_, &As[sl_][0] + 4096 + lOF);                \
        gl2lds16(gB0 + k0_, &Bs[sl_][0] + lOF);                       \
        gl2lds16(gB1 + k0_, &Bs[sl_][0] + 4096 + lOF);                \
    }

    // One opaque asm block: 8x ds_read_b128 + lgkmcnt(0). Early-clobber
    // outputs (no aliasing with address inputs). MFMAs consume the outputs
    // by SSA -> cannot be hoisted above the wait (rule #18 satisfied).
#define READ8(aAdr, bAdr, a0, a1, a2, a3, b0, b1, b2, b3)             \
    asm volatile(                                                     \
        "ds_read_b128 %0, %8 offset:0\n\t"                            \
        "ds_read_b128 %1, %8 offset:1024\n\t"                         \
        "ds_read_b128 %2, %8 offset:2048\n\t"                         \
        "ds_read_b128 %3, %8 offset:3072\n\t"                         \
        "ds_read_b128 %4, %9 offset:0\n\t"                            \
        "ds_read_b128 %5, %9 offset:1024\n\t"                         \
        "ds_read_b128 %6, %9 offset:2048\n\t"                         \
        "ds_read_b128 %7, %9 offset:3072\n\t"                         \
        "s_waitcnt lgkmcnt(0)"                                        \
        : "=&v"(a0), "=&v"(a1), "=&v"(a2), "=&v"(a3),                 \
          "=&v"(b0), "=&v"(b1), "=&v"(b2), "=&v"(b3)                  \
        : "v"(aAdr), "v"(bAdr))

#define MFMAS(a0, a1, a2, a3, b0, b1, b2, b3) {                       \
        int32x4_t av_[4] = {a0, a1, a2, a3};                          \
        int32x4_t bv_[4] = {b0, b1, b2, b3};                          \
        __builtin_amdgcn_s_setprio(1);                                \
        _Pragma("unroll")                                             \
        for (int i_ = 0; i_ < 4; ++i_)                                \
            _Pragma("unroll")                                         \
            for (int j_ = 0; j_ < 4; ++j_)                            \
                iacc[i_][j_] = __builtin_amdgcn_mfma_i32_16x16x64_i8( \
                    av_[i_], bv_[j_], iacc[i_][j_], 0, 0, 0);         \
        __builtin_amdgcn_s_setprio(0);                                \
    }

    // BODY(s): [STAGE(s+3)] ; vmcnt leaves 3 stages in flight ; barrier
    // publishes slot s ; opaque read+lgkm0 ; 16 MFMA ; barrier frees slot
    // s&3 for STAGE(s+4) (issued by whichever wave reaches body s+1 first).
#define BODY(s, VMN, DOSTAGE) {                                       \
        if (DOSTAGE) STAGE((s) + 3);                                  \
        WAITVM(VMN);                                                  \
        __builtin_amdgcn_s_barrier();                                 \
        const unsigned sl_ = (unsigned)((s) & 3) * 8192u;             \
        int32x4_t a0_, a1_, a2_, a3_, b0_, b1_, b2_, b3_;             \
        READ8(asBase + sl_ + aOff0, bsBase + sl_ + bOff0,             \
              a0_, a1_, a2_, a3_, b0_, b1_, b2_, b3_);                \
        MFMAS(a0_, a1_, a2_, a3_, b0_, b1_, b2_, b3_);                \
        __builtin_amdgcn_s_barrier();                                 \
    }

    // ---- prologue: 12 DMAs in flight ----
    STAGE(0); STAGE(1); STAGE(2);

    // ---- steady state: bodies 0..60 stage s+3, wait vmcnt(12) ----
    for (int s = 0; s <= NSLICE - 4; ++s)
        BODY(s, 12, 1);
    // ---- tail: 61/62/63 drain 8/4/0 ----
    BODY(NSLICE - 3, 8, 0);
    BODY(NSLICE - 2, 4, 0);
    BODY(NSLICE - 1, 0, 0);

    // --- epilogue: C/D layout col=lane&15, row=lquad*4+reg ---
    float fn[4], wf[4], bb[4];
    int ncol[4];
#pragma unroll
    for (int j = 0; j < 4; ++j) {
        const int ncl = wcl * 64 + j * 16 + lrow;
        ncol[j] = bn * BN + ncl;
        fn[j] = fws_s[ncl];
        wf[j] = wsf_s[ncl];
        bb[j] = bias[ncol[j]];
    }
    const int m0 = bm * BM + wr * 64;
#pragma unroll
    for (int i = 0; i < 4; ++i) {
#pragma unroll
        for (int r = 0; r < 4; ++r) {
            const int m = m0 + i * 16 + lquad * 4 + r;
            const float xs  = xscale[m];
            const float czp = xzpc[m];
            float* orow = out + (size_t)m * N_DIM;
#pragma unroll
            for (int j = 0; j < 4; ++j)
                orow[ncol[j]] = xs * (fn[j] * (float)iacc[i][j][r] + czp * wf[j]) + bb[j];
        }
    }
#undef BODY
#undef MFMAS
#undef READ8
#undef STAGE
}

extern "C" void kernel_launch(void* const* d_in, const int* in_sizes, int n_in,
                              void* d_out, int out_size, void* d_ws, size_t ws_size,
                              hipStream_t stream) {
    const float* x     = (const float*)d_in[0];
    const int*   qw    = (const int*)d_in[1];
    const float* wsc   = (const float*)d_in[2];
    const int*   wzp   = (const int*)d_in[3];
    const float* bias  = (const float*)d_in[4];
    float* out = (float*)d_out;

    // workspace layout
    char* A8  = (char*)d_ws;                                   //  8 MiB
    char* Bt8 = A8 + (size_t)M_DIM * K_DIM;                    // 16 MiB
    float* xscale = (float*)(Bt8 + (size_t)N_DIM * K_DIM);     //  8 KiB
    float* xzpc   = xscale + M_DIM;                            //  8 KiB
    int*   Sw     = (int*)(xzpc + M_DIM);                      // 512 KiB

    prep_kernel<<<QUANT_BLOCKS + DEQ_BLOCKS, 256, 0, stream>>>(
        x, qw, wsc, wzp, A8, Bt8, xscale, xzpc, Sw);
    dim3 grid(N_DIM / BN, M_DIM / BM);
    gemm_kernel<<<grid, 256, 0, stream>>>(A8, Bt8, xscale, xzpc, wsc, Sw, bias, out);
}

// Round 6
// 171.131 us; speedup vs baseline: 1.0295x; 1.0295x over previous
//
#include <hip/hip_runtime.h>
#include <stdint.h>

#define M_DIM 2048
#define N_DIM 4096
#define K_DIM 4096
#define NGROUP 32
#define GSIZE 128

#define RQ_UP   (127.0f / 15.0f)   // weight requant gain
#define RQ_DOWN (15.0f / 127.0f)

// ---------------------------------------------------------------------------
// R6: geometry/staging identical to R4/R5 (128x128 tile, 4 waves 2Mx2N, wave
// 64x64 = 4x4 frags of 16x16x64 i8 MFMA, 4 LDS slots, distance-3 DMA
// prefetch, 2 blocks/CU). CHANGE: register double-buffer of fragments so the
// LDS pipe runs DURING the MFMA cluster:
//   body(s): STAGE(s+3); vmcnt(8); barrier; READ8(s+1)->setB; lgkmcnt(8)
//            [slice-s reads confirmed, 8 new reads left in flight];
//            sched_barrier; MFMA(setA); barrier.
// R0-R5 all put ds_read and MFMA in the same phase -> measured 1913 cyc/step
// = LDS(~1000) + MFMA(653) + barriers, fully serialized (both resident
// blocks phase-lock via shared-LDS contention). Overlap floor ~1200 cyc.
// ---------------------------------------------------------------------------
#define BM 128
#define BN 128
#define KSLICE 64
#define NSLICE (K_DIM / KSLICE)    // 64
#define ASLOT (BM * KSLICE)        //  8 KiB
#define BSLOT (BN * KSLICE)        //  8 KiB

typedef __attribute__((ext_vector_type(4))) int int32x4_t;

static __device__ __forceinline__ void gl2lds16(const void* g, void* l) {
    auto gp = (const __attribute__((address_space(1))) unsigned int*)(uintptr_t)g;
    auto lp = (__attribute__((address_space(3))) unsigned int*)(uintptr_t)l;
    __builtin_amdgcn_global_load_lds(gp, lp, 16, 0, 0);
}

// bare counted waits (no "memory" clobber -> no forced vmcnt(0) drain),
// pinned with sched_barrier(0) so nothing migrates across them (rule #18).
#define WAITVM_(N) asm volatile("s_waitcnt vmcnt(" #N ")")
#define WAITVM(N)                                   \
    do {                                            \
        __builtin_amdgcn_sched_barrier(0);          \
        WAITVM_(N);                                 \
        __builtin_amdgcn_sched_barrier(0);          \
    } while (0)
#define WAITLGKM_(N) asm volatile("s_waitcnt lgkmcnt(" #N ")")
#define WAITLGKM(N)                                 \
    do {                                            \
        __builtin_amdgcn_sched_barrier(0);          \
        WAITLGKM_(N);                               \
        __builtin_amdgcn_sched_barrier(0);          \
    } while (0)
#define BARRIER()                                   \
    do {                                            \
        __builtin_amdgcn_sched_barrier(0);          \
        __builtin_amdgcn_s_barrier();               \
        __builtin_amdgcn_sched_barrier(0);          \
    } while (0)

// ---------------------------------------------------------------------------
// Fused prep (unchanged from R5):
//   [0, 2048): per-token activation quant -> A8 = (q-128) int8, xscale, czp
//   [2048, ..): weight requant; rsn computed in-cluster via shfl_xor max.
// ---------------------------------------------------------------------------
#define QUANT_BLOCKS M_DIM
#define DEQ_BLOCKS ((N_DIM * K_DIM) / 8 / 256)       // 8 codes / thread

__global__ __launch_bounds__(256) void prep_kernel(
        const float* __restrict__ x,
        const int* __restrict__ qw,          // [N][K] codes 0..15 as int32
        const float* __restrict__ wsc,       // [N][32]
        const int* __restrict__ wzp,         // [N][32]
        char* __restrict__ A8,               // [M][K] int8 (q-128)
        char* __restrict__ Bt8,              // [N][K] int8 requantized
        float* __restrict__ xscale,          // [M]
        float* __restrict__ xzpc,            // [M]  = 128 - zp
        int* __restrict__ Sw)                // [N][32] group sums of Bt8
{
    const int t = threadIdx.x;
    if (blockIdx.x < QUANT_BLOCKS) {
        const int s = blockIdx.x;
        const float* xrow = x + (size_t)s * K_DIM;

        float xv[16];
        float vmin = 1e38f, vmax = -1e38f;
#pragma unroll
        for (int p = 0; p < 4; ++p) {
            float4 v = *((const float4*)(xrow + p * 1024) + t);
            xv[p*4+0] = v.x; xv[p*4+1] = v.y; xv[p*4+2] = v.z; xv[p*4+3] = v.w;
            vmin = fminf(vmin, fminf(fminf(v.x, v.y), fminf(v.z, v.w)));
            vmax = fmaxf(vmax, fmaxf(fmaxf(v.x, v.y), fmaxf(v.z, v.w)));
        }
#pragma unroll
        for (int off = 32; off > 0; off >>= 1) {
            vmin = fminf(vmin, __shfl_xor(vmin, off));
            vmax = fmaxf(vmax, __shfl_xor(vmax, off));
        }
        __shared__ float smin[4], smax[4];
        const int wave = t >> 6;
        if ((t & 63) == 0) { smin[wave] = vmin; smax[wave] = vmax; }
        __syncthreads();
        vmin = fminf(fminf(smin[0], smin[1]), fminf(smin[2], smin[3]));
        vmax = fmaxf(fmaxf(smax[0], smax[1]), fmaxf(smax[2], smax[3]));

        float sc = (vmax - vmin) / 255.0f;
        sc = fmaxf(sc, 1e-5f);
        float zp = rintf(-vmin / sc);
        zp = fminf(fmaxf(zp, 0.0f), 255.0f);
        const float inv_sc = 1.0f / sc;

#pragma unroll
        for (int p = 0; p < 4; ++p) {
            int b[4];
#pragma unroll
            for (int e = 0; e < 4; ++e) {
                float q = fminf(fmaxf(rintf(xv[p*4+e] * inv_sc) + zp, 0.0f), 255.0f);
                b[e] = (int)q - 128;
            }
            unsigned pack = (b[0] & 0xff) | ((b[1] & 0xff) << 8) |
                            ((b[2] & 0xff) << 16) | ((b[3] & 0xff) << 24);
            *(unsigned*)(A8 + (size_t)s * K_DIM + p * 1024 + t * 4) = pack;
        }
        if (t == 0) { xscale[s] = sc; xzpc[s] = 128.0f - zp; }
    } else {
        // ---- weight requant: 8 codes/thread; 16-lane cluster = 1 group ----
        const size_t base = ((size_t)(blockIdx.x - QUANT_BLOCKS) * 256 + t) * 8;
        const int n = (int)(base >> 12);          // /4096
        const int g = (int)((base >> 7) & 31);
        const int zp = wzp[n * NGROUP + g];

        // inline rsn: row max of the 32 scales across the 16-lane cluster
        const int cl = t & 15;
        float2 wp = *(const float2*)(wsc + (size_t)n * NGROUP + cl * 2);
        float smx = fmaxf(wp.x, wp.y);
#pragma unroll
        for (int off = 1; off < 16; off <<= 1)
            smx = fmaxf(smx, __shfl_xor(smx, off));
        const float factor = wsc[n * NGROUP + g] * (RQ_UP / smx);   // <= 127/15

        int4 c0 = *(const int4*)(qw + base);
        int4 c1 = *(const int4*)(qw + base + 4);
        int w[8];
        w[0] = (int)rintf((float)(c0.x - zp) * factor);
        w[1] = (int)rintf((float)(c0.y - zp) * factor);
        w[2] = (int)rintf((float)(c0.z - zp) * factor);
        w[3] = (int)rintf((float)(c0.w - zp) * factor);
        w[4] = (int)rintf((float)(c1.x - zp) * factor);
        w[5] = (int)rintf((float)(c1.y - zp) * factor);
        w[6] = (int)rintf((float)(c1.z - zp) * factor);
        w[7] = (int)rintf((float)(c1.w - zp) * factor);
        uint2 pk;
        pk.x = (w[0] & 0xff) | ((w[1] & 0xff) << 8) | ((w[2] & 0xff) << 16) | ((w[3] & 0xff) << 24);
        pk.y = (w[4] & 0xff) | ((w[5] & 0xff) << 8) | ((w[6] & 0xff) << 16) | ((w[7] & 0xff) << 24);
        *(uint2*)(Bt8 + base) = pk;

        int s8 = w[0] + w[1] + w[2] + w[3] + w[4] + w[5] + w[6] + w[7];
#pragma unroll
        for (int off = 1; off < 16; off <<= 1) s8 += __shfl_xor(s8, off);
        if ((t & 15) == 0)
            Sw[n * NGROUP + g] = s8;     // coalesced, no atomic
    }
}

// ---------------------------------------------------------------------------
// Pipelined i8 GEMM, 2 blocks/CU, fragment register double-buffer with
// counted lgkmcnt so ds_read drains during the MFMA cluster.
// Epilogue: out[m][n] = xscale[m]*(fws[n]*iacc + czp[m]*WSf[n]) + bias[n]
// ---------------------------------------------------------------------------
__global__ __launch_bounds__(256, 2) void gemm_kernel(
        const char* __restrict__ A8,     // [M][K] int8
        const char* __restrict__ Bt8,    // [N][K] int8
        const float* __restrict__ xscale,
        const float* __restrict__ xzpc,
        const float* __restrict__ wsc,   // [N][32]
        const int* __restrict__ Sw,      // [N][32]
        const float* __restrict__ bias,  // [N]
        float* __restrict__ out)         // [M][N] f32
{
    __shared__ __align__(16) char As[4][ASLOT];   // 32 KiB
    __shared__ __align__(16) char Bs[4][BSLOT];   // 32 KiB
    __shared__ float fws_s[BN], wsf_s[BN];

    const int tid  = threadIdx.x;
    const int bn   = blockIdx.x;
    const int bm   = blockIdx.y;
    const int wave = tid >> 6;           // 0..3
    const int lane = tid & 63;
    const int wr   = wave >> 1;          // 0..1 -> 64-row band
    const int wcl  = wave & 1;           // 0..1 -> 64-col band
    const int lrow  = lane & 15;
    const int lquad = lane >> 4;         // 0..3 -> 16B k-chunk

    // --- per-column epilogue constants, before the pipeline starts ---
    if (tid < BN) {
        const int n = bn * BN + tid;
        const int4* s4 = (const int4*)(Sw + (size_t)n * NGROUP);
        int acc = 0;
#pragma unroll
        for (int p = 0; p < 8; ++p) { int4 v = s4[p]; acc += v.x + v.y + v.z + v.w; }
        const float4* w4 = (const float4*)(wsc + (size_t)n * NGROUP);
        float s = 0.f;
#pragma unroll
        for (int p = 0; p < 8; ++p) {
            float4 w = w4[p];
            s = fmaxf(s, fmaxf(fmaxf(w.x, w.y), fmaxf(w.z, w.w)));
        }
        const float fw = s * RQ_DOWN;
        fws_s[tid] = fw;
        wsf_s[tid] = fw * (float)acc;
    }
    // drain once to a clean vmcnt/lgkm baseline for the counted waits
    __builtin_amdgcn_sched_barrier(0);
    asm volatile("s_waitcnt vmcnt(0) lgkmcnt(0)");
    __builtin_amdgcn_sched_barrier(0);

    // --- staging: gl2lds dst = uniform base + lane*16 (m104). Each DMA
    // covers 16 rows x 64B; wave w instr p covers rows (p*4+w)*16.. ---
    const char* Ab = A8  + (size_t)(bm * BM) * K_DIM;
    const char* Bb = Bt8 + (size_t)(bn * BN) * K_DIM;
    const int lsub = lane >> 2;                    // row within 16-row slab
    const int csrc = (lane & 3) ^ ((lane >> 3) & 3);
    const char* gA0 = Ab + (size_t)((wave * 16     ) + lsub) * K_DIM + csrc * 16;
    const char* gA1 = Ab + (size_t)((wave * 16 + 64) + lsub) * K_DIM + csrc * 16;
    const char* gB0 = Bb + (size_t)((wave * 16     ) + lsub) * K_DIM + csrc * 16;
    const char* gB1 = Bb + (size_t)((wave * 16 + 64) + lsub) * K_DIM + csrc * 16;
    const int lOF = wave * 1024;                   // + 4096 for the +64-row slab

    // --- ds_read addresses (LDS 32-bit), swizzle matches staging ---
    const int xq = (lquad ^ ((lrow >> 1) & 3)) * 16;
    const unsigned asBase = (unsigned)(uintptr_t)&As[0][0];
    const unsigned bsBase = (unsigned)(uintptr_t)&Bs[0][0];
    const unsigned aOff0 = (unsigned)((wr  * 64 + lrow) * KSLICE + xq);
    const unsigned bOff0 = (unsigned)((wcl * 64 + lrow) * KSLICE + xq);

    int32x4_t iacc[4][4];
    const int32x4_t zi = {0, 0, 0, 0};
#pragma unroll
    for (int i = 0; i < 4; ++i)
#pragma unroll
        for (int j = 0; j < 4; ++j) iacc[i][j] = zi;

#define STAGE(t) {                                                    \
        const int sl_ = (t) & 3;                                      \
        const size_t k0_ = (size_t)(t) * KSLICE;                      \
        gl2lds16(gA0 + k0_, &As[sl_][0] + lOF);                       \
        gl2lds16(gA1 + k0_, &As[sl_][0] + 4096 + lOF);                \
        gl2lds16(gB0 + k0_, &Bs[sl_][0] + lOF);                       \
        gl2lds16(gB1 + k0_, &Bs[sl_][0] + 4096 + lOF);                \
    }

    // Opaque asm: 8x ds_read_b128, NO internal wait — reads stay in flight;
    // completion is confirmed by the NEXT body's counted lgkmcnt(8).
    // Early-clobber outputs stay allocated until their MFMA uses (SSA).
#define READ8(aAdr, bAdr, a0, a1, a2, a3, b0, b1, b2, b3)             \
    asm volatile(                                                     \
        "ds_read_b128 %0, %8 offset:0\n\t"                            \
        "ds_read_b128 %1, %8 offset:1024\n\t"                         \
        "ds_read_b128 %2, %8 offset:2048\n\t"                         \
        "ds_read_b128 %3, %8 offset:3072\n\t"                         \
        "ds_read_b128 %4, %9 offset:0\n\t"                            \
        "ds_read_b128 %5, %9 offset:1024\n\t"                         \
        "ds_read_b128 %6, %9 offset:2048\n\t"                         \
        "ds_read_b128 %7, %9 offset:3072"                             \
        : "=&v"(a0), "=&v"(a1), "=&v"(a2), "=&v"(a3),                 \
          "=&v"(b0), "=&v"(b1), "=&v"(b2), "=&v"(b3)                  \
        : "v"(aAdr), "v"(bAdr))

#define MFMAS(a0, a1, a2, a3, b0, b1, b2, b3) {                       \
        int32x4_t av_[4] = {a0, a1, a2, a3};                          \
        int32x4_t bv_[4] = {b0, b1, b2, b3};                          \
        __builtin_amdgcn_s_setprio(1);                                \
        _Pragma("unroll")                                             \
        for (int i_ = 0; i_ < 4; ++i_)                                \
            _Pragma("unroll")                                         \
            for (int j_ = 0; j_ < 4; ++j_)                            \
                iacc[i_][j_] = __builtin_amdgcn_mfma_i32_16x16x64_i8( \
                    av_[i_], bv_[j_], iacc[i_][j_], 0, 0, 0);         \
        __builtin_amdgcn_s_setprio(0);                                \
    }

    // frag register sets (named even/odd — rule #20)
    int32x4_t aA0, aA1, aA2, aA3, bA0, bA1, bA2, bA3;   // set A
    int32x4_t aB0, aB1, aB2, aB3, bB0, bB1, bB2, bB3;   // set B

    // BODY(s): see header comment. Hazards:
    //  - publish slot (s+1)&3: vmcnt(VMN) covers its 4 DMAs + barrier.
    //  - free slot s&3 for STAGE(s+4): this body's lgkm(8) confirms slice-s
    //    reads done, trailing barrier makes it cross-wave.
#define BODY(s, VMN, DOSTAGE, CA0,CA1,CA2,CA3,CB0,CB1,CB2,CB3,        \
             NA0,NA1,NA2,NA3,NB0,NB1,NB2,NB3) {                       \
        if (DOSTAGE) STAGE((s) + 3);                                  \
        WAITVM(VMN);                                                  \
        BARRIER();                                                    \
        const unsigned sl_ = (unsigned)(((s) + 1) & 3) * 8192u;       \
        READ8(asBase + sl_ + aOff0, bsBase + sl_ + bOff0,             \
              NA0, NA1, NA2, NA3, NB0, NB1, NB2, NB3);                \
        WAITLGKM(8);                                                  \
        MFMAS(CA0, CA1, CA2, CA3, CB0, CB1, CB2, CB3);                \
        BARRIER();                                                    \
    }

    // ---- prologue: 12 DMAs in flight; land slice 0; read frags(0)->A ----
    STAGE(0); STAGE(1); STAGE(2);
    WAITVM(8);                  // slice 0's 4 DMAs done (own-wave count)
    BARRIER();                  // cross-wave publish slot 0 (+ fws/wsf)
    READ8(asBase + aOff0, bsBase + bOff0,
          aA0, aA1, aA2, aA3, bA0, bA1, bA2, bA3);

    // ---- steady state: bodies 0..59 in even/odd pairs (vmcnt 8) ----
    for (int s = 0; s < NSLICE - 4; s += 2) {
        BODY(s,     8, 1, aA0,aA1,aA2,aA3,bA0,bA1,bA2,bA3,
                          aB0,aB1,aB2,aB3,bB0,bB1,bB2,bB3);
        BODY(s + 1, 8, 1, aB0,aB1,aB2,aB3,bB0,bB1,bB2,bB3,
                          aA0,aA1,aA2,aA3,bA0,bA1,bA2,bA3);
    }
    // ---- tail: bodies 60..63 ----
    BODY(60, 8, 1, aA0,aA1,aA2,aA3,bA0,bA1,bA2,bA3,      // STAGE(63)
                   aB0,aB1,aB2,aB3,bB0,bB1,bB2,bB3);
    BODY(61, 4, 0, aB0,aB1,aB2,aB3,bB0,bB1,bB2,bB3,      // wait slice 62
                   aA0,aA1,aA2,aA3,bA0,bA1,bA2,bA3);
    BODY(62, 0, 0, aA0,aA1,aA2,aA3,bA0,bA1,bA2,bA3,      // wait slice 63
                   aB0,aB1,aB2,aB3,bB0,bB1,bB2,bB3);
    // body 63: no read, final MFMA on set B
    WAITLGKM(0);
    MFMAS(aB0,aB1,aB2,aB3,bB0,bB1,bB2,bB3);

    // --- epilogue: C/D layout col=lane&15, row=lquad*4+reg ---
    float fn[4], wf[4], bb[4];
    int ncol[4];
#pragma unroll
    for (int j = 0; j < 4; ++j) {
        const int ncl = wcl * 64 + j * 16 + lrow;
        ncol[j] = bn * BN + ncl;
        fn[j] = fws_s[ncl];
        wf[j] = wsf_s[ncl];
        bb[j] = bias[ncol[j]];
    }
    const int m0 = bm * BM + wr * 64;
#pragma unroll
    for (int i = 0; i < 4; ++i) {
#pragma unroll
        for (int r = 0; r < 4; ++r) {
            const int m = m0 + i * 16 + lquad * 4 + r;
            const float xs  = xscale[m];
            const float czp = xzpc[m];
            float* orow = out + (size_t)m * N_DIM;
#pragma unroll
            for (int j = 0; j < 4; ++j)
                orow[ncol[j]] = xs * (fn[j] * (float)iacc[i][j][r] + czp * wf[j]) + bb[j];
        }
    }
#undef BODY
#undef MFMAS
#undef READ8
#undef STAGE
}

extern "C" void kernel_launch(void* const* d_in, const int* in_sizes, int n_in,
                              void* d_out, int out_size, void* d_ws, size_t ws_size,
                              hipStream_t stream) {
    const float* x     = (const float*)d_in[0];
    const int*   qw    = (const int*)d_in[1];
    const float* wsc   = (const float*)d_in[2];
    const int*   wzp   = (const int*)d_in[3];
    const float* bias  = (const float*)d_in[4];
    float* out = (float*)d_out;

    // workspace layout
    char* A8  = (char*)d_ws;                                   //  8 MiB
    char* Bt8 = A8 + (size_t)M_DIM * K_DIM;                    // 16 MiB
    float* xscale = (float*)(Bt8 + (size_t)N_DIM * K_DIM);     //  8 KiB
    float* xzpc   = xscale + M_DIM;                            //  8 KiB
    int*   Sw     = (int*)(xzpc + M_DIM);                      // 512 KiB

    prep_kernel<<<QUANT_BLOCKS + DEQ_BLOCKS, 256, 0, stream>>>(
        x, qw, wsc, wzp, A8, Bt8, xscale, xzpc, Sw);
    dim3 grid(N_DIM / BN, M_DIM / BM);
    gemm_kernel<<<grid, 256, 0, stream>>>(A8, Bt8, xscale, xzpc, wsc, Sw, bias, out);
}